// Round 8
// baseline (146.811 us; speedup 1.0000x reference)
//
#include <hip/hip_runtime.h>

#define HH 64
#define WW 64

typedef _Float16 f16;
typedef f16 f16x8 __attribute__((ext_vector_type(8)));
typedef f16 f16x4 __attribute__((ext_vector_type(4)));
typedef float f32x4 __attribute__((ext_vector_type(4)));

// ws: ws[0..63] = fp32 logit bias; then f16 region (offsets in halves):
#define M1_H 0         // [c][r*4+s][lane][j] : 49152
#define BU_H 49152     // [c][r*4+s][lane][j] : 49152
#define BF_H 98304     // [g][r][lane][j]     : 12288
#define BC_H 110592    // [c2][s][lane][j]    : 4096
#define PREP_N (64 + 114688)

__global__ __launch_bounds__(256) void prep_kernel(
    const float* __restrict__ attw, const float* __restrict__ ctw,
    const float* __restrict__ ctb, const float* __restrict__ few,
    const float* __restrict__ caw, float* __restrict__ ws) {
  int i = blockIdx.x * 256 + threadIdx.x;
  if (i >= PREP_N) return;
  f16* hb = (f16*)(ws + 64);
  if (i < 64) {
    int s = i >> 4, l15 = i & 15;
    int o = 2 * s + (l15 >> 3), n = l15 & 7;
    float acc = 0.f;
    for (int c = 0; c < 8; ++c)
      for (int d = 0; d < 8; ++d)
        acc += ctb[c * 64 + d * 8 + n] * attw[d * 512 + c * 64 + n * 8 + o];
    ws[i] = acc;
    return;
  }
  int z = i - 64;
  if (z < BU_H) {
    int j = z & 7, lane = (z >> 3) & 63, rest = z >> 9;
    int rs = rest % 12, c = rest / 12;
    int r = rs >> 2, s = rs & 3;
    int q = lane >> 4, l15 = lane & 15;
    int t = r * 4 + q;
    int o = 2 * s + (l15 >> 3), n = l15 & 7;
    float acc = 0.f;
    if (t < 9)
      for (int d = 0; d < 8; ++d)
        acc += ctw[(t * 8 + j) * 512 + c * 64 + d * 8 + n] *
               attw[d * 512 + c * 64 + n * 8 + o];
    hb[M1_H + z] = (f16)acc;
  } else if (z < BF_H) {
    int z2 = z - BU_H;
    int j = z2 & 7, lane = (z2 >> 3) & 63, rest = z2 >> 9;
    int rs = rest % 12, c = rest / 12;
    int r = rs >> 2, s = rs & 3;
    int q = lane >> 4, l15 = lane & 15;
    int t = r * 4 + q;
    int d = 2 * s + (l15 >> 3), n = l15 & 7;
    float v = (t < 9) ? ctw[(t * 8 + j) * 512 + c * 64 + d * 8 + n] : 0.f;
    hb[z] = (f16)v;
  } else if (z < BC_H) {
    int z2 = z - BF_H;
    int j = z2 & 7, lane = (z2 >> 3) & 63, rest = z2 >> 9;
    int r = rest % 3, g = rest / 3;
    int q = lane >> 4, l15 = lane & 15;
    int t = r * 4 + q;
    int d = 2 * (j & 3) + (j >> 2);
    float v = 0.f;
    if (t < 9 && ((l15 >> 3) == (g & 1)))
      v = few[(t * 8 + d) * 64 + g * 8 + (l15 & 7)];
    hb[z] = (f16)v;
  } else if (z < 114688) {
    int z2 = z - BC_H;
    int j = z2 & 7, lane = (z2 >> 3) & 63, rest = z2 >> 9;
    int s = rest & 3, c2 = rest >> 2;
    int q = lane >> 4, l15 = lane & 15;
    int nk = c2 * 4 + q;
    int nc = 2 * s + (l15 >> 3);
    float v = (nk == nc) ? caw[j * 64 + nc * 8 + (l15 & 7)] : 0.f;
    hb[z] = (f16)v;
  }
}

// Fused kernel: v computed on the 18x10 halo grid (12 M-tiles, 3/wave) from a
// 20x12 double-halo input tile, then FeaExt+CapsAct run against LDS vtile —
// the vt global round-trip (16MB write + 21MB read + stage2 fill + launch gap)
// is gone. v-GEMM structure = R1-proven (register B rotation, LDS attb fold).
// vtile writes select zeros for out-of-image pixels (reference zero-pads v).
// [R8 = R7 resubmitted verbatim: R7's bench was an infra failure (container
// acquisition), the kernel never ran.]
__global__ __launch_bounds__(256, 2) void caps_fused(
    const float* __restrict__ in, const float* __restrict__ ws,
    const float* __restrict__ ctb, const float* __restrict__ fb,
    const float* __restrict__ cab, float* __restrict__ out) {
  // region A (34816 B): xt2[241*72]f16 (34704) / h1t[128*72]f16 / outbuf[128*68]f32
  // region B (27648 B): attb[192*72]f16 / vtile[192*72]f16
  __shared__ float smemA[8704];
  __shared__ f16 smemB[13824];
  f16* xt2 = (f16*)smemA;
  f16* attb = smemB;

  int bid = blockIdx.x;
  int b = bid >> 5, t5 = bid & 31;
  int ty = t5 >> 3, tx = t5 & 7;
  int tid = threadIdx.x;
  int w = __builtin_amdgcn_readfirstlane(tid >> 6);
  int lane = tid & 63;
  int q = lane >> 4, l15 = lane & 15;
  int h = l15 >> 3, n = l15 & 7;

  const f16* hb = (const f16*)(ws + 64);
  const f16x8* m1v = (const f16x8*)(hb + M1_H);
  const f16x8* buv = (const f16x8*)(hb + BU_H);
  const f16x8* bfv = (const f16x8*)(hb + BF_H);
  const f16x8* bcv = (const f16x8*)(hb + BC_H);
  const float* lb = ws;

  // ---- fill double-halo input tile: rows rp=hy2*12+hx2 (20x12), row 240=0 ----
#pragma unroll
  for (int k = 0; k < 8; ++k) {
    int i = tid + k * 256;
    if (i < 241 * 8) {
      int c = i & 7, rp = i >> 3;
      float xs[8] = {0.f, 0.f, 0.f, 0.f, 0.f, 0.f, 0.f, 0.f};
      if (rp < 240) {
        int hy2 = rp / 12, hx2 = rp - hy2 * 12;
        int iy = ty * 16 + hy2 - 2, ix = tx * 8 + hx2 - 2;
        if (iy >= 0 && iy < HH && ix >= 0 && ix < WW) {
          const float* src = in + (((b * HH + iy) * WW + ix) * 64 + c);
#pragma unroll
          for (int d = 0; d < 8; ++d) xs[d] = src[d * 8];
        }
      }
      f16x8 pk;
#pragma unroll
      for (int d = 0; d < 8; ++d) pk[d] = (f16)xs[d];
      *(f16x8*)&xt2[rp * 72 + c * 8] = pk;
    }
  }

  // ---- per-lane A-row offsets for the 3 v-tiles (pixel hp = m*16 + l15) ----
  int hpt3[3][3];
#pragma unroll
  for (int i2 = 0; i2 < 3; ++i2) {
    int hp = (3 * w + i2) * 16 + l15;
    int pv = hp < 180;
    int hy = hp / 10, hx = hp - hy * 10;
#pragma unroll
    for (int r = 0; r < 3; ++r) {
      int t = r * 4 + q;
      int off = 240 * 72;
      if (t < 9 && pv) {
        int ky = t / 3, kx = t - ky * 3;
        off = ((hy + ky) * 12 + hx + kx) * 72;
      }
      hpt3[i2][r] = off;
    }
  }

  // ---- pass 1: logits GEMM over 3 tiles/wave, register B rotation ----
  f32x4 L[3][4];
#pragma unroll
  for (int s = 0; s < 4; ++s) {
    float v0 = lb[s * 16 + l15];
    L[0][s] = (f32x4){v0, v0, v0, v0};
    L[1][s] = (f32x4){v0, v0, v0, v0};
    L[2][s] = (f32x4){v0, v0, v0, v0};
  }
  __syncthreads();  // xt2 ready

  f16x8 bmA[12], bmB[12];
#pragma unroll
  for (int rs = 0; rs < 12; ++rs) bmA[rs] = m1v[rs * 64 + lane];

  auto p1step = [&](int c, const f16x8(&bm)[12]) {
#pragma unroll
    for (int i2 = 0; i2 < 3; ++i2) {
      f16x8 a[3];
#pragma unroll
      for (int r = 0; r < 3; ++r)
        a[r] = *(const f16x8*)&xt2[hpt3[i2][r] + c * 8];
#pragma unroll
      for (int s = 0; s < 4; ++s)
#pragma unroll
        for (int r = 0; r < 3; ++r)
          L[i2][s] = __builtin_amdgcn_mfma_f32_16x16x32_f16(
              a[r], bm[r * 4 + s], L[i2][s], 0, 0, 0);
    }
  };

#pragma unroll 1
  for (int cc = 0; cc < 4; ++cc) {
    int c0 = 2 * cc;
#pragma unroll
    for (int rs = 0; rs < 12; ++rs)
      bmB[rs] = m1v[((c0 + 1) * 12 + rs) * 64 + lane];
    p1step(c0, bmA);
    if (cc < 3) {
#pragma unroll
      for (int rs = 0; rs < 12; ++rs)
        bmA[rs] = m1v[((c0 + 2) * 12 + rs) * 64 + lane];
    }
    p1step(c0 + 1, bmB);
  }

  // ---- cross-pass prefetch BU(c=0) + bias, then softmax -> attb ----
  f16x8 buA[12], buB[12];
#pragma unroll
  for (int rs = 0; rs < 12; ++rs) buA[rs] = buv[rs * 64 + lane];
  float cbA[4], cbB[4];
#pragma unroll
  for (int s = 0; s < 4; ++s) cbA[s] = ctb[s * 16 + l15];

#pragma unroll
  for (int i2 = 0; i2 < 3; ++i2) {
    int pbase = (3 * w + i2) * 16 + q * 4;
#pragma unroll
    for (int r = 0; r < 4; ++r) {
      float v0 = L[i2][0][r], v1 = L[i2][1][r], v2 = L[i2][2][r], v3 = L[i2][3][r];
      float pm = fmaxf(fmaxf(v0, v1), fmaxf(v2, v3));
      float m = fmaxf(pm, __shfl_xor(pm, 8));
      float e0 = __expf(v0 - m), e1 = __expf(v1 - m);
      float e2 = __expf(v2 - m), e3 = __expf(v3 - m);
      float ps = e0 + e1 + e2 + e3;
      float inv = 1.f / (ps + __shfl_xor(ps, 8));
      int ab = (pbase + r) * 72 + n * 8 + h;  // o = 2s + h
      attb[ab + 0] = (f16)(e0 * inv);
      attb[ab + 2] = (f16)(e1 * inv);
      attb[ab + 4] = (f16)(e2 * inv);
      attb[ab + 6] = (f16)(e3 * inv);
    }
  }
  __syncthreads();

  int ab2[3][4];
#pragma unroll
  for (int i2 = 0; i2 < 3; ++i2)
#pragma unroll
    for (int r = 0; r < 4; ++r)
      ab2[i2][r] = ((3 * w + i2) * 16 + q * 4 + r) * 72 + n * 8;

  // ---- pass 2: u GEMM + attention fold ----
  f32x4 V[3][4];
#pragma unroll
  for (int i2 = 0; i2 < 3; ++i2)
#pragma unroll
    for (int s = 0; s < 4; ++s) V[i2][s] = (f32x4){0.f, 0.f, 0.f, 0.f};

  auto p2step = [&](int c, const f16x8(&bu)[12], const float(&cb)[4]) {
#pragma unroll
    for (int i2 = 0; i2 < 3; ++i2) {
      f16x8 a[3];
#pragma unroll
      for (int r = 0; r < 3; ++r)
        a[r] = *(const f16x8*)&xt2[hpt3[i2][r] + c * 8];
      f32x4 U[4];
#pragma unroll
      for (int s = 0; s < 4; ++s) U[s] = (f32x4){cb[s], cb[s], cb[s], cb[s]};
#pragma unroll
      for (int s = 0; s < 4; ++s)
#pragma unroll
        for (int r = 0; r < 3; ++r)
          U[s] = __builtin_amdgcn_mfma_f32_16x16x32_f16(
              a[r], bu[r * 4 + s], U[s], 0, 0, 0);
#pragma unroll
      for (int r = 0; r < 4; ++r) {
        float af = (float)attb[ab2[i2][r] + c];
#pragma unroll
        for (int s = 0; s < 4; ++s) V[i2][s][r] += U[s][r] * af;
      }
    }
  };

#pragma unroll 1
  for (int cc = 0; cc < 4; ++cc) {
    int c0 = 2 * cc;
#pragma unroll
    for (int rs = 0; rs < 12; ++rs)
      buB[rs] = buv[((c0 + 1) * 12 + rs) * 64 + lane];
#pragma unroll
    for (int s = 0; s < 4; ++s) cbB[s] = ctb[(c0 + 1) * 64 + s * 16 + l15];
    p2step(c0, buA, cbA);
    if (cc < 3) {
#pragma unroll
      for (int rs = 0; rs < 12; ++rs)
        buA[rs] = buv[((c0 + 2) * 12 + rs) * 64 + lane];
#pragma unroll
      for (int s = 0; s < 4; ++s) cbA[s] = ctb[(c0 + 2) * 64 + s * 16 + l15];
    }
    p2step(c0 + 1, buB, cbB);
  }

  // ---- v -> vtile (aliases attb), zeros for pad/out-of-image pixels ----
  __syncthreads();  // all attb fold-reads complete
  f16* vtile = smemB;
#pragma unroll
  for (int i2 = 0; i2 < 3; ++i2)
#pragma unroll
    for (int r = 0; r < 4; ++r) {
      int p = (3 * w + i2) * 16 + q * 4 + r;
      int hy = p / 10, hx = p - hy * 10;
      int gy = ty * 16 + hy - 1, gx = tx * 8 + hx - 1;
      bool val = (p < 180) && gy >= 0 && gy < HH && gx >= 0 && gx < WW;
      f16x4 st;
#pragma unroll
      for (int s = 0; s < 4; ++s)
        st[s] = val ? (f16)V[i2][s][r] : (f16)0.f;  // slot=h*4+s, d=2s+h
      *(f16x4*)&vtile[p * 72 + n * 8 + h * 4] = st;
    }
  __syncthreads();  // vtile ready (row 180 = zeros via pad-row writes)

  // ================= stage2 body (verbatim, vtile in LDS) =================
  int j7 = l15 & 7;
  int hpt[2][3];
#pragma unroll
  for (int i2 = 0; i2 < 2; ++i2) {
    int pyA = (2 * w + i2) * 2 + h;
#pragma unroll
    for (int r = 0; r < 3; ++r) {
      int t = r * 4 + q;
      int hp = 180;
      if (t < 9) {
        int ky = t / 3, kx = t - ky * 3;
        hp = (pyA + ky) * 10 + j7 + kx;
      }
      hpt[i2][r] = hp * 72;
    }
  }

  // FeaExt: col (n=2s+h, j=j7); input chunk g feeds only s = g>>1
  f32x4 Lf[2][4];
#pragma unroll
  for (int s = 0; s < 4; ++s) {
    float bvv = fb[(2 * s + h) * 8 + j7];
    Lf[0][s] = (f32x4){bvv, bvv, bvv, bvv};
    Lf[1][s] = (f32x4){bvv, bvv, bvv, bvv};
  }
#pragma unroll
  for (int g = 0; g < 8; ++g) {
    int sg = g >> 1;
#pragma unroll
    for (int r = 0; r < 3; ++r) {
      f16x8 bf = bfv[(g * 3 + r) * 64 + lane];
#pragma unroll
      for (int i2 = 0; i2 < 2; ++i2) {
        f16x8 a = *(const f16x8*)&vtile[hpt[i2][r] + g * 8];
        Lf[i2][sg] =
            __builtin_amdgcn_mfma_f32_16x16x32_f16(a, bf, Lf[i2][sg], 0, 0, 0);
      }
    }
  }
#pragma unroll
  for (int i2 = 0; i2 < 2; ++i2)
#pragma unroll
    for (int s = 0; s < 4; ++s)
#pragma unroll
      for (int r = 0; r < 4; ++r) Lf[i2][s][r] = fmaxf(Lf[i2][s][r], 0.f);

  __syncthreads();  // vtile + xt2 reads done; alias h1t over xt2 region
  f16* h1t = (f16*)smemA;  // [128][72], ch2 = n*8 + j1
#pragma unroll
  for (int i2 = 0; i2 < 2; ++i2)
#pragma unroll
    for (int s = 0; s < 4; ++s)
#pragma unroll
      for (int r = 0; r < 4; ++r)
        h1t[((2 * w + i2) * 16 + q * 4 + r) * 72 + (2 * s + h) * 8 + j7] =
            (f16)Lf[i2][s][r];
  __syncthreads();

  // CapsAct: K=64 over (j1, n) block-diag
  f32x4 Hc[2][4];
#pragma unroll
  for (int s = 0; s < 4; ++s) {
    float bvv = cab[(2 * s + h) * 8 + j7];
    Hc[0][s] = (f32x4){bvv, bvv, bvv, bvv};
    Hc[1][s] = (f32x4){bvv, bvv, bvv, bvv};
  }
#pragma unroll
  for (int c2 = 0; c2 < 2; ++c2) {
    f16x8 a2[2];
#pragma unroll
    for (int i2 = 0; i2 < 2; ++i2)
      a2[i2] = *(const f16x8*)&h1t[((2 * w + i2) * 16 + l15) * 72 + c2 * 32 + q * 8];
#pragma unroll
    for (int s = 0; s < 4; ++s) {
      f16x8 bc = bcv[(c2 * 4 + s) * 64 + lane];
#pragma unroll
      for (int i2 = 0; i2 < 2; ++i2)
        Hc[i2][s] =
            __builtin_amdgcn_mfma_f32_16x16x32_f16(a2[i2], bc, Hc[i2][s], 0, 0, 0);
    }
  }

  __syncthreads();  // h1t reads done; alias outbuf over region A
  float* outbuf = smemA;  // [128][68], ch = j2*8 + n
#pragma unroll
  for (int i2 = 0; i2 < 2; ++i2)
#pragma unroll
    for (int s = 0; s < 4; ++s)
#pragma unroll
      for (int r = 0; r < 4; ++r)
        outbuf[((2 * w + i2) * 16 + q * 4 + r) * 68 + j7 * 8 + 2 * s + h] =
            Hc[i2][s][r];
  __syncthreads();

  for (int idx = tid; idx < 2048; idx += 256) {
    int p = idx >> 4, q4 = idx & 15;
    float4 val = *(float4*)&outbuf[p * 68 + q4 * 4];
    int gy = ty * 16 + (p >> 3), gx = tx * 8 + (p & 7);
    *(float4*)(out + ((b * HH + gy) * WW + gx) * 64 + q4 * 4) = val;
  }
}

extern "C" void kernel_launch(void* const* d_in, const int* in_sizes, int n_in,
                              void* d_out, int out_size, void* d_ws, size_t ws_size,
                              hipStream_t stream) {
  const float* inputs = (const float*)d_in[0];
  const float* attw   = (const float*)d_in[1];
  const float* ctw    = (const float*)d_in[2];
  const float* ctb    = (const float*)d_in[3];
  const float* few    = (const float*)d_in[4];
  const float* fb     = (const float*)d_in[5];
  const float* caw    = (const float*)d_in[6];
  const float* cab    = (const float*)d_in[7];
  float* out = (float*)d_out;
  float* ws  = (float*)d_ws;

  prep_kernel<<<(PREP_N + 255) / 256, 256, 0, stream>>>(attw, ctw, ctb, few, caw, ws);
  caps_fused<<<32 * 32, 256, 0, stream>>>(inputs, ws, ctb, fb, cab, out);
}